// Round 6
// baseline (1268.501 us; speedup 1.0000x reference)
//
#include <hip/hip_runtime.h>
#include <math.h>

#define NBLK 64
#define NTHR 576        // 9 waves: 8 compute + 1 fire/job wave
#define LSEQ 1024

typedef unsigned int u32;
typedef unsigned short u16;
typedef unsigned long long u64;

// ---------------- scalar helpers ----------------
__device__ __forceinline__ float bf2f(u16 u){ union{u32 i;float f;}v; v.i=(u32)u<<16; return v.f; }
__device__ __forceinline__ u16 f2bf(float f){ union{float f;u32 i;}v; v.f=f; u32 x=v.i;
  return (u16)((x + 0x7fffu + ((x>>16)&1u)) >> 16); }
__device__ __forceinline__ float u2f(u32 u){ union{u32 i;float f;}v; v.i=u; return v.f; }
__device__ __forceinline__ u32  f2u(float f){ union{float f;u32 i;}v; v.f=f; return v.i; }
__device__ __forceinline__ float sigm(float x){ return 1.f/(1.f+__expf(-x)); }

// coherent (agent-scope) 8B atoms: (tag<<32)|payload
__device__ __forceinline__ u64 gld64(const u64* p){ return __hip_atomic_load(const_cast<u64*>(p), __ATOMIC_RELAXED, __HIP_MEMORY_SCOPE_AGENT); }
__device__ __forceinline__ void gst64(u64* p, u64 v){ __hip_atomic_store(p, v, __ATOMIC_RELAXED, __HIP_MEMORY_SCOPE_AGENT); }
__device__ __forceinline__ u64 pollt(const u64* p, u32 tag){
  u64 v; int n = 0;
  do { v = gld64(p); } while ((u32)(v>>32) != tag && ++n < (1<<20));
  return v;
}

// ---------------- reductions ----------------
// DPP full-wave(64) sum; result uniform. VALU-only.
__device__ __forceinline__ float wred(float a){
  a += __int_as_float(__builtin_amdgcn_update_dpp(0, __float_as_int(a), 0x111, 0xf, 0xf, true));
  a += __int_as_float(__builtin_amdgcn_update_dpp(0, __float_as_int(a), 0x112, 0xf, 0xf, true));
  a += __int_as_float(__builtin_amdgcn_update_dpp(0, __float_as_int(a), 0x114, 0xf, 0xf, true));
  a += __int_as_float(__builtin_amdgcn_update_dpp(0, __float_as_int(a), 0x118, 0xf, 0xf, true));
  a += __int_as_float(__builtin_amdgcn_update_dpp(0, __float_as_int(a), 0x142, 0xa, 0xf, true));
  a += __int_as_float(__builtin_amdgcn_update_dpp(0, __float_as_int(a), 0x143, 0xc, 0xf, true));
  return __int_as_float(__builtin_amdgcn_readlane(__float_as_int(a), 63));
}
__device__ __forceinline__ float wredsh(float a){
  #pragma unroll
  for (int off = 32; off; off >>= 1) a += __shfl_xor(a, off);
  return a;
}
__device__ __forceinline__ float wredmaxsh(float a){
  #pragma unroll
  for (int off = 32; off; off >>= 1) a = fmaxf(a, __shfl_xor(a, off));
  return a;
}

// ---------------- packed dot helpers ----------------
__device__ __forceinline__ float dot8p(uint4 w, float4 a, float4 b2){
  float s;
  s  = u2f(w.x<<16)*a.x  + u2f(w.x&0xffff0000u)*a.y;
  s += u2f(w.y<<16)*a.z  + u2f(w.y&0xffff0000u)*a.w;
  s += u2f(w.z<<16)*b2.x + u2f(w.z&0xffff0000u)*b2.y;
  s += u2f(w.w<<16)*b2.z + u2f(w.w&0xffff0000u)*b2.w;
  return s;
}
__device__ __forceinline__ float dot4f(float4 w, float4 x){
  return w.x*x.x + w.y*x.y + w.z*x.z + w.w*x.w;
}
__device__ __forceinline__ uint4 pk8(float4 a, float4 b2){
  uint4 r;
  r.x = (u32)f2bf(a.x)  | ((u32)f2bf(a.y)<<16);
  r.y = (u32)f2bf(a.z)  | ((u32)f2bf(a.w)<<16);
  r.z = (u32)f2bf(b2.x) | ((u32)f2bf(b2.y)<<16);
  r.w = (u32)f2bf(b2.z) | ((u32)f2bf(b2.w)<<16);
  return r;
}

#define SMEM_BYTES 156288

// wave 8: fire prev-phase cross-block atoms, then run lagged softmax jobs.
// Order: dB (uses sA from prior dA) BEFORE dA (overwrites sA).
#define W8_FIRE_AND_JOBS() do { \
  if (wv == 8){ \
    int par1_ = (int)((ph-1)&1); \
    if (d0V){ \
      float pl0 = 0.f, pl1 = 0.f; \
      _Pragma("unroll") for (int k = 0; k < 8; ++k){ \
        float qk = s_q8[par1_*8 + k]; \
        pl0 += s_kloc[k*128 + lane]      * qk; \
        pl1 += s_kloc[k*128 + lane + 64] * qk; } \
      gst64(&XP[((size_t)(d0Slot*64 + lane))*64 + b], ((u64)d0Tag<<32) | (u32)f2bf(pl0) | ((u32)f2bf(pl1)<<16)); \
    } \
    if (e0V && lane == 0){ \
      float p0 = 0.f, p1 = 0.f; \
      _Pragma("unroll") for (int i = 0; i < 8; ++i){ p0 += s_red[par1_*16 + i*2]; p1 += s_red[par1_*16 + i*2+1]; } \
      gst64(&XE[e0Slot*64 + b], ((u64)e0Tag<<32) | (u32)f2bf(p0) | ((u32)f2bf(p1)<<16)); \
    } \
    if (d2V && b == d2o1){ /* dB: final dest log-softmax */ \
      u64 v_ = pollt(XS + d2Slot*64 + lane, d2Tag); \
      float x0 = sA0 + bf2f((u16)(v_ & 0xffff)); \
      float x1 = sA1 + bf2f((u16)((v_>>16) & 0xffff)); \
      x0 = (lane < d2cur)      ? x0 : -__builtin_inff(); \
      x1 = (lane + 64 < d2cur) ? x1 : -__builtin_inff(); \
      float m_ = wredmaxsh(fmaxf(x0, x1)); \
      float s_ = wredsh(__expf(x0 - m_) + __expf(x1 - m_)); \
      float la_ = (d2arg < 64) ? __shfl(x0, d2arg) : __shfl(x1, d2arg - 64); \
      if (lane == 0) nllw += (m_ + logf(s_)) - la_; \
    } \
    if (d1V && (b == d1o1 || b == d1o2)){ /* dA: sum partials over 32 blocks */ \
      const u64* P_ = XP + ((size_t)(d1Slot*64 + lane))*64 + ((b == d1o2) ? 32 : 0); \
      float h0_ = 0.f, h1_ = 0.f; \
      for (int c_ = 0; c_ < 2; ++c_){ \
        u64 vv_[16]; int bad_; int nn_ = 0; \
        do { bad_ = 0; \
          _Pragma("unroll") for (int j_ = 0; j_ < 16; ++j_) vv_[j_] = gld64(P_ + c_*16 + j_); \
          _Pragma("unroll") for (int j_ = 0; j_ < 16; ++j_) bad_ |= ((u32)(vv_[j_]>>32) != d1Tag); \
        } while (bad_ && ++nn_ < (1<<20)); \
        _Pragma("unroll") for (int j_ = 0; j_ < 16; ++j_){ \
          h0_ += bf2f((u16)(vv_[j_] & 0xffff)); h1_ += bf2f((u16)((vv_[j_]>>16) & 0xffff)); } \
      } \
      if (b == d1o2) gst64(XS + d1Slot*64 + lane, ((u64)d1Tag<<32) | (u32)f2bf(h0_) | ((u32)f2bf(h1_)<<16)); \
      else { sA0 = h0_; sA1 = h1_; } \
    } \
    if (e1V && b == e1Own){ /* ae: 2-way edge log-softmax */ \
      u64 v_ = pollt(XE + e1Slot*64 + lane, e1Tag); \
      float p0_ = wredsh(bf2f((u16)(v_ & 0xffff))); \
      float p1_ = wredsh(bf2f((u16)((v_>>16) & 0xffff))); \
      if (lane == 0){ \
        float l0_ = p0_ + be2_0, l1_ = p1_ + be2_1; \
        float m_ = fmaxf(l0_, l1_); \
        nllw += m_ + logf(__expf(l0_-m_) + __expf(l1_-m_)) - (e1Sel ? l1_ : l0_); \
      } \
    } \
  } \
} while(0)

#define SHIFT2() do { \
  d2V=d1V; d2Slot=d1Slot; d2o1=d1o1; d2Tag=d1Tag; d2cur=d1cur; d2arg=d1arg; \
  d1V=d0V; d1Slot=d0Slot; d1o1=d0o1; d1o2=d0o2; d1Tag=d0Tag; d1cur=d0cur; d1arg=d0arg; \
  d0V=0; \
  e1V=e0V; e1Slot=e0Slot; e1Own=e0Own; e1Tag=e0Tag; e1Sel=e0Sel; \
  e0V=0; \
} while(0)

__global__ void __launch_bounds__(NTHR, 1)
dgmg_kernel(const int* __restrict__ actions, const int* __restrict__ argseq,
            const float* __restrict__ node_init, const float* __restrict__ w_nip, const float* __restrict__ b_nip,
            const float* __restrict__ w_e1, const float* __restrict__ b_e1,
            const float* __restrict__ w_e2, const float* __restrict__ b_e2,
            const float* __restrict__ w_q, const float* __restrict__ b_q,
            const float* __restrict__ w_k,
            const float* __restrict__ wih_n, const float* __restrict__ whh_n,
            const float* __restrict__ bih_n, const float* __restrict__ bhh_n,
            const float* __restrict__ wih_g, const float* __restrict__ whh_g,
            const float* __restrict__ bih_g, const float* __restrict__ bhh_g,
            const float* __restrict__ graph0,
            float* __restrict__ out, unsigned char* __restrict__ ws)
{
  extern __shared__ unsigned char smem[];
  u16* s_wihg = (u16*)smem;                 // [24][512] packed bf16
  u16* s_whhg = s_wihg + 24*512;
  u16* s_wihn = s_whhg + 24*512;
  u16* s_whhn = s_wihn + 24*512;
  u16* s_we1  = s_whhn + 24*512;            // [8][1024]
  u16* s_wq   = s_we1 + 8*1024;             // [8][1024]
  float* s_g    = (float*)(s_wq + 8*1024);  // [2][512] staged g (parity)
  float* s_nc   = s_g + 1024;               // [2][512] staged ncur (parity)
  float* s_curv = s_nc + 1024;              // [2][512] current node vec (parity)
  float* s_h0   = s_curv + 1024;            // [512] fresh-node embedding
  float* s_kloc = s_h0 + 512;               // [8][128] k-cache transposed [dim][node]
  float* s_bihg = s_kloc + 1024;            // [24]
  float* s_bhhg = s_bihg + 24;
  float* s_bihn = s_bhhg + 24;
  float* s_bhhn = s_bihn + 24;
  float* s_be1  = s_bhhn + 24;              // [8]
  float* s_bq   = s_be1 + 8;                // [8]
  float* s_q8   = s_bq + 8;                 // [2][8] (parity)
  float* s_red  = s_q8 + 16;                // [2][16] (parity)
  u16*   s_gin  = (u16*)(s_red + 32);       // [128][24] gi_n freeze cache (bf16)

  const int b = blockIdx.x, tid = threadIdx.x;
  const int wv = tid >> 6, lane = tid & 63;
  const int d = b*8 + ((wv < 8) ? wv : 0);

  // workspace: tagged u64 atoms (layout identical to round 5)
  u64* Xng = (u64*)ws;         // [2][512][2]: per dim {ncur, g} adjacent
  u64* Xh  = Xng + 2048;       // [512] h0 broadcast
  u64* XE  = Xh + 512;         // [4][64] edge-logit partials
  u64* XP  = XE + 256;         // [4][64][64] dest-logit partials
  u64* XS  = XP + 16384;       // [4][64] dest half-sums
  u64* XN  = XS + 256;         // [64] final nll pieces

  // ---------------- init: biases + packed bf16 weight slices ----------------
  if (tid < 24){
    int ld = tid/3, gt = tid%3;
    int row = gt*512 + b*8 + ld;
    s_bihg[tid] = bih_g[row]; s_bhhg[tid] = bhh_g[row];
    s_bihn[tid] = bih_n[row]; s_bhhn[tid] = bhh_n[row];
  }
  if (tid < 8){ s_be1[tid] = b_e1[b*8+tid]; s_bq[tid] = b_q[b*8+tid]; }

  for (int r = wv; r < 24; r += 9){
    int ld = r/3, gt = r%3;
    long grow = (long)(gt*512 + b*8 + ld) * 512;
    float4 a0, a1;
    a0 = *(const float4*)&wih_g[grow + lane*8]; a1 = *(const float4*)&wih_g[grow + lane*8 + 4];
    *(uint4*)&s_wihg[r*512 + lane*8] = pk8(a0, a1);
    a0 = *(const float4*)&whh_g[grow + lane*8]; a1 = *(const float4*)&whh_g[grow + lane*8 + 4];
    *(uint4*)&s_whhg[r*512 + lane*8] = pk8(a0, a1);
    a0 = *(const float4*)&wih_n[grow + lane*8]; a1 = *(const float4*)&wih_n[grow + lane*8 + 4];
    *(uint4*)&s_wihn[r*512 + lane*8] = pk8(a0, a1);
    a0 = *(const float4*)&whh_n[grow + lane*8]; a1 = *(const float4*)&whh_n[grow + lane*8 + 4];
    *(uint4*)&s_whhn[r*512 + lane*8] = pk8(a0, a1);
  }
  if (wv < 8){
    long grow = (long)(b*8 + wv) * 1024;
    #pragma unroll
    for (int h = 0; h < 2; ++h){
      float4 a0 = *(const float4*)&w_e1[grow + h*512 + lane*8];
      float4 a1 = *(const float4*)&w_e1[grow + h*512 + lane*8 + 4];
      *(uint4*)&s_we1[wv*1024 + h*512 + lane*8] = pk8(a0, a1);
      float4 q0 = *(const float4*)&w_q[grow + h*512 + lane*8];
      float4 q1 = *(const float4*)&w_q[grow + h*512 + lane*8 + 4];
      *(uint4*)&s_wq[wv*1024 + h*512 + lane*8] = pk8(q0, q1);
    }
  }
  float we2_0 = w_e2[d], we2_1 = w_e2[512+d];
  float be2_0 = b_e2[0], be2_1 = b_e2[1];
  float nllw = 0.f, sA0 = 0.f, sA1 = 0.f;

  // job/fire pipeline state (uniform trace walk)
  int d0V=0,d0Slot=0,d0o1=0,d0o2=0,d0cur=0,d0arg=0; u32 d0Tag=0;
  int d1V=0,d1Slot=0,d1o1=0,d1o2=0,d1cur=0,d1arg=0; u32 d1Tag=0;
  int d2V=0,d2Slot=0,d2o1=0,d2cur=0,d2arg=0; u32 d2Tag=0;
  int e0V=0,e0Slot=0,e0Own=0,e0Sel=0; u32 e0Tag=0;
  int e1V=0,e1Slot=0,e1Own=0,e1Sel=0; u32 e1Tag=0;
  int ecnt=0, dcnt=0;

  // ---------------- INIT (tag 1): broadcast h0 ----------------
  if (tid < 512) s_g[tid] = node_init[tid];   // scratch (slot 0)
  __syncthreads();
  float cbg_r=0,cbg_z=0,bg_ni=0,bg_nh=0, bh_gr=0,bh_gz=0;
  float bn_r=0,bn_z=0,bn_nh=0, fb_r=0,fb_z=0,fb_n=0, be1w=0,bqw=0;
  if (wv < 8){
    cbg_r = s_bihg[wv*3+0]+s_bhhg[wv*3+0];
    cbg_z = s_bihg[wv*3+1]+s_bhhg[wv*3+1];
    bg_ni = s_bihg[wv*3+2]; bg_nh = s_bhhg[wv*3+2];
    bh_gr = s_bhhg[wv*3+0]; bh_gz = s_bhhg[wv*3+1];
    bn_r = s_bhhn[wv*3+0]; bn_z = s_bhhn[wv*3+1]; bn_nh = s_bhhn[wv*3+2];
    fb_r = s_bihn[wv*3+0]; fb_z = s_bihn[wv*3+1]; fb_n = s_bihn[wv*3+2];
    be1w = s_be1[wv]; bqw = s_bq[wv];
    const float* wr = w_nip + (long)d*512;
    float4 wa = *(const float4*)&wr[lane*8], wb2 = *(const float4*)&wr[lane*8+4];
    float4 xa = *(float4*)&s_g[lane*8], xb = *(float4*)&s_g[lane*8+4];
    float h0d = wred(dot4f(wa,xa)+dot4f(wb2,xb)) + b_nip[d];
    if (lane == 0) gst64(&Xh[d], (1ull<<32) | f2u(h0d));
  }
  __syncthreads();
  u32 ph = 2;

  float gi0r=0,gi0z=0,gi0n=0, ghn0r=0,ghn0z=0,ghn0n=0;
  int cur = -1, have_se = 0;
  bool first_an = true;

  // ---------------- main sequential scan ----------------
  for (int t = 0; t < LSEQ; ++t){
    int a = actions[t];
    if (a == 1) continue;
    if (a == 3){ have_se = 1; continue; }
    if (a < 0 || a >= 4) continue;

    int t1 = (t+1 < LSEQ) ? actions[t+1] : -1;
    int nxt = (t1 == 1);
    int i2 = (t+2 < LSEQ) ? t+2 : LSEQ-1;
    int chn = nxt ? argseq[i2] : 0;

    u32 tg = ph-1; int par1 = tg & 1, par = ph & 1;

    if (a == 0){ // ======== ADD_NODE: 1 phase, 1 barrier ========
      if (first_an){
        if (tid < 512){ u64 v = pollt(&Xh[tid], 1u); s_h0[tid] = u2f((u32)v); s_g[par1*512+tid] = graph0[tid]; }
      } else {
        if (tid < 512){ u64 v = pollt(&Xng[(par1*512+tid)*2+1], tg); s_g[par1*512+tid] = u2f((u32)v); }
      }
      __syncthreads();
      W8_FIRE_AND_JOBS();
      if (wv < 8){
        float4 xg_a = *(float4*)&s_g[par1*512+lane*8], xg_b = *(float4*)&s_g[par1*512+lane*8+4];
        float4 xc_a = *(float4*)&s_curv[par1*512+lane*8], xc_b = *(float4*)&s_curv[par1*512+lane*8+4];
        const u32* Whg = (const u32*)s_whhg;
        if (first_an){
          float4 xh_a = *(float4*)&s_h0[lane*8], xh_b = *(float4*)&s_h0[lane*8+4];
          const u32* Wig = (const u32*)s_wihg; const u32* Wn = (const u32*)s_whhn;
          gi0r = wred(dot8p(*(const uint4*)&Wig[(wv*3+0)*256+lane*4], xh_a,xh_b)) + s_bihg[wv*3+0];
          gi0z = wred(dot8p(*(const uint4*)&Wig[(wv*3+1)*256+lane*4], xh_a,xh_b)) + s_bihg[wv*3+1];
          gi0n = wred(dot8p(*(const uint4*)&Wig[(wv*3+2)*256+lane*4], xh_a,xh_b)) + s_bihg[wv*3+2];
          ghn0r = wred(dot8p(*(const uint4*)&Wn[(wv*3+0)*256+lane*4], xh_a,xh_b)) + bn_r;
          ghn0z = wred(dot8p(*(const uint4*)&Wn[(wv*3+1)*256+lane*4], xh_a,xh_b)) + bn_z;
          ghn0n = wred(dot8p(*(const uint4*)&Wn[(wv*3+2)*256+lane*4], xh_a,xh_b)) + bn_nh;
        }
        { // fire g' FIRST (critical chain)
          float ghr = wred(dot8p(*(const uint4*)&Whg[(wv*3+0)*256+lane*4], xg_a,xg_b)) + bh_gr;
          float ghz = wred(dot8p(*(const uint4*)&Whg[(wv*3+1)*256+lane*4], xg_a,xg_b)) + bh_gz;
          float ghn = wred(dot8p(*(const uint4*)&Whg[(wv*3+2)*256+lane*4], xg_a,xg_b)) + bg_nh;
          float r_ = sigm(gi0r + ghr), z_ = sigm(gi0z + ghz);
          float n_ = tanhf(gi0n + r_*ghn);
          if (lane == 0) gst64(&Xng[((ph&1)*512+d)*2+1], ((u64)ph<<32) | f2u((1.f-z_)*n_ + z_*s_g[par1*512+d]));
        }
        float fr=0.f, fz=0.f, fn=0.f;
        if (cur >= 0){ // freeze prev node (block-local caches) BEFORE lookahead read
          const u32* Win = (const u32*)s_wihn;
          fr = wred(dot8p(*(const uint4*)&Win[(wv*3+0)*256+lane*4], xc_a,xc_b)) + fb_r;
          fz = wred(dot8p(*(const uint4*)&Win[(wv*3+1)*256+lane*4], xc_a,xc_b)) + fb_z;
          fn = wred(dot8p(*(const uint4*)&Win[(wv*3+2)*256+lane*4], xc_a,xc_b)) + fb_n;
          const float* wkr = w_k + (long)d*512;
          float4 ka = *(const float4*)&wkr[lane*8], kb2 = *(const float4*)&wkr[lane*8+4];
          float kv = wred(dot4f(ka,xc_a)+dot4f(kb2,xc_b));
          if (lane == 0){
            s_gin[cur*24+wv*3+0] = f2bf(fr); s_gin[cur*24+wv*3+1] = f2bf(fz); s_gin[cur*24+wv*3+2] = f2bf(fn);
            s_kloc[wv*128 + cur] = kv;
          }
        }
        if (nxt){ // ncur1 = GRU_n(chosen1, h0); forward freeze regs if chn==cur
          float gr = (chn == cur) ? fr : bf2f(s_gin[chn*24+wv*3+0]);
          float gz = (chn == cur) ? fz : bf2f(s_gin[chn*24+wv*3+1]);
          float gn = (chn == cur) ? fn : bf2f(s_gin[chn*24+wv*3+2]);
          float r2 = sigm(gr + ghn0r), z2 = sigm(gz + ghn0z);
          float n2 = tanhf(gn + r2*ghn0n);
          if (lane == 0) gst64(&Xng[((ph&1)*512+d)*2], ((u64)ph<<32) | f2u((1.f-z2)*n2 + z2*s_h0[d]));
        }
        if (have_se){ // deferred STOP_EDGE e-partials -> s_red[par]
          const u32* Re = (const u32*)s_we1 + wv*512;
          float pe = dot8p(*(const uint4*)&Re[lane*4], xg_a,xg_b) + dot8p(*(const uint4*)&Re[256+lane*4], xc_a,xc_b);
          float hv = fmaxf(wred(pe) + be1w, 0.f);
          if (lane == 0){ s_red[par*16 + wv*2] = hv*we2_0; s_red[par*16 + wv*2+1] = hv*we2_1; }
        }
      }
      if (tid < 512) s_curv[par*512+tid] = s_h0[tid];
      SHIFT2();
      if (have_se){ e0V=1; e0Slot=ecnt&3; e0Sel=1; e0Own=ecnt&63; e0Tag=ph; ecnt++; }
      have_se = 0; first_an = false;
      cur += 1; ph += 1;
    }
    else { // ======== CHOOSE_DEST: 1 phase, 1 barrier ========
      int arg = argseq[t];
      if (tid < 512){
        const u64* p = &Xng[(par1*512 + tid)*2];
        u64 v0, v1; int n = 0;
        do { v0 = gld64(p); v1 = gld64(p+1); }
        while ((((u32)(v0>>32) != tg) || ((u32)(v1>>32) != tg)) && ++n < (1<<20));
        s_nc[par1*512+tid] = u2f((u32)v0); s_g[par1*512+tid] = u2f((u32)v1);
      }
      __syncthreads();
      W8_FIRE_AND_JOBS();
      if (wv < 8){
        float4 xn_a = *(float4*)&s_nc[par1*512+lane*8], xn_b = *(float4*)&s_nc[par1*512+lane*8+4];
        float4 xg_a = *(float4*)&s_g[par1*512+lane*8],  xg_b = *(float4*)&s_g[par1*512+lane*8+4];
        float4 xc_a = *(float4*)&s_curv[par1*512+lane*8], xc_b = *(float4*)&s_curv[par1*512+lane*8+4];
        const u32* Wn = (const u32*)s_whhn; const u32* Wig = (const u32*)s_wihg; const u32* Whg = (const u32*)s_whhg;
        { // 1) fire g_j FIRST (critical chain)
          float pr = dot8p(*(const uint4*)&Wig[(wv*3+0)*256+lane*4], xn_a,xn_b)
                   + dot8p(*(const uint4*)&Whg[(wv*3+0)*256+lane*4], xg_a,xg_b);
          float pz = dot8p(*(const uint4*)&Wig[(wv*3+1)*256+lane*4], xn_a,xn_b)
                   + dot8p(*(const uint4*)&Whg[(wv*3+1)*256+lane*4], xg_a,xg_b);
          float r_ = sigm(wred(pr) + cbg_r);
          float z_ = sigm(wred(pz) + cbg_z);
          float gin_ = wred(dot8p(*(const uint4*)&Wig[(wv*3+2)*256+lane*4], xn_a,xn_b)) + bg_ni;
          float ghn_ = wred(dot8p(*(const uint4*)&Whg[(wv*3+2)*256+lane*4], xg_a,xg_b)) + bg_nh;
          float n_ = tanhf(gin_ + r_*ghn_);
          if (lane == 0) gst64(&Xng[((ph&1)*512+d)*2+1], ((u64)ph<<32) | f2u((1.f-z_)*n_ + z_*s_g[par1*512+d]));
        }
        if (nxt){ // 2) fire ncur_{j+1} = GRU_n(chosen_{j+1}, ncur_j)
          float ghr = wred(dot8p(*(const uint4*)&Wn[(wv*3+0)*256+lane*4], xn_a,xn_b)) + bn_r;
          float ghz = wred(dot8p(*(const uint4*)&Wn[(wv*3+1)*256+lane*4], xn_a,xn_b)) + bn_z;
          float ghn = wred(dot8p(*(const uint4*)&Wn[(wv*3+2)*256+lane*4], xn_a,xn_b)) + bn_nh;
          float gr = bf2f(s_gin[chn*24+wv*3+0]), gz = bf2f(s_gin[chn*24+wv*3+1]), gn = bf2f(s_gin[chn*24+wv*3+2]);
          float r_ = sigm(gr+ghr), z_ = sigm(gz+ghz);
          float n_ = tanhf(gn + r_*ghn);
          if (lane == 0) gst64(&Xng[((ph&1)*512+d)*2], ((u64)ph<<32) | f2u((1.f-z_)*n_ + z_*s_nc[par1*512+d]));
        }
        { // 3) q_j + AE e-partials from (g_{j-1}, curv_{j-1}) -> parity LDS
          const u32* Rq = (const u32*)s_wq + wv*512;
          float pq = dot8p(*(const uint4*)&Rq[lane*4], xg_a,xg_b) + dot8p(*(const uint4*)&Rq[256+lane*4], xc_a,xc_b);
          float qd = wred(pq) + bqw;
          const u32* Re = (const u32*)s_we1 + wv*512;
          float pe = dot8p(*(const uint4*)&Re[lane*4], xg_a,xg_b) + dot8p(*(const uint4*)&Re[256+lane*4], xc_a,xc_b);
          float hv = fmaxf(wred(pe) + be1w, 0.f);
          if (lane == 0){ s_q8[par*8+wv] = qd; s_red[par*16+wv*2] = hv*we2_0; s_red[par*16+wv*2+1] = hv*we2_1; }
        }
      }
      if (tid < 512) s_curv[par*512+tid] = s_nc[par1*512+tid];
      SHIFT2();
      e0V=1; e0Slot=ecnt&3; e0Sel=0; e0Own=ecnt&63; e0Tag=ph; ecnt++;
      d0V=1; d0Slot=dcnt&3; d0o1=(2*dcnt)&63; d0o2=(2*dcnt+1)&63; d0cur=cur; d0arg=arg; d0Tag=ph; dcnt++;
      ph += 1;
    }
  }

  // ---------------- drain: D1 (final SE partials), D2, D3 (flush jobs) ----------------
  {
    u32 tg = ph-1; int par1 = tg & 1, par = ph & 1;
    if (tid < 512){ u64 v = pollt(&Xng[(par1*512+tid)*2+1], tg); s_g[par1*512+tid] = u2f((u32)v); }
    __syncthreads();
    W8_FIRE_AND_JOBS();
    if (have_se && wv < 8){
      float4 xg_a = *(float4*)&s_g[par1*512+lane*8], xg_b = *(float4*)&s_g[par1*512+lane*8+4];
      float4 xc_a = *(float4*)&s_curv[par1*512+lane*8], xc_b = *(float4*)&s_curv[par1*512+lane*8+4];
      const u32* Re = (const u32*)s_we1 + wv*512;
      float pe = dot8p(*(const uint4*)&Re[lane*4], xg_a,xg_b) + dot8p(*(const uint4*)&Re[256+lane*4], xc_a,xc_b);
      float hv = fmaxf(wred(pe) + be1w, 0.f);
      if (lane == 0){ s_red[par*16+wv*2] = hv*we2_0; s_red[par*16+wv*2+1] = hv*we2_1; }
    }
    SHIFT2();
    if (have_se){ e0V=1; e0Slot=ecnt&3; e0Sel=1; e0Own=ecnt&63; e0Tag=ph; ecnt++; }
    ph += 1;
  }
  #pragma unroll 1
  for (int dp = 0; dp < 2; ++dp){
    __syncthreads();
    W8_FIRE_AND_JOBS();
    SHIFT2();
    ph += 1;
  }
  // ---------------- final collect ----------------
  if (wv == 8){
    if (lane == 0) gst64(&XN[b], (0xFFFFull<<32) | f2u(nllw));
    if (b == 0){
      u64 v = pollt(&XN[lane], 0xFFFFu);
      float tot = wredsh(u2f((u32)v));
      if (lane == 0) out[0] = tot;
    }
  }
}

extern "C" void kernel_launch(void* const* d_in, const int* in_sizes, int n_in,
                              void* d_out, int out_size, void* d_ws, size_t ws_size,
                              hipStream_t stream) {
  (void)in_sizes; (void)n_in; (void)out_size; (void)ws_size;
  // zero all tag-atom regions (19520 u64) — exact-match tags then poison/replay-safe
  hipMemsetAsync(d_ws, 0, 156160, stream);
  hipFuncSetAttribute((const void*)dgmg_kernel,
                      hipFuncAttributeMaxDynamicSharedMemorySize, SMEM_BYTES);
  dgmg_kernel<<<NBLK, NTHR, SMEM_BYTES, stream>>>(
      (const int*)d_in[0], (const int*)d_in[1],
      (const float*)d_in[2], (const float*)d_in[3], (const float*)d_in[4],
      (const float*)d_in[5], (const float*)d_in[6],
      (const float*)d_in[7], (const float*)d_in[8],
      (const float*)d_in[9], (const float*)d_in[10],
      (const float*)d_in[11],                      /* w_k ; b_k unused (cancels) */
      (const float*)d_in[13], (const float*)d_in[14],
      (const float*)d_in[15], (const float*)d_in[16],
      (const float*)d_in[17], (const float*)d_in[18],
      (const float*)d_in[19], (const float*)d_in[20],
      (const float*)d_in[21],
      (float*)d_out, (unsigned char*)d_ws);
}

// Round 7
// 1219.902 us; speedup vs baseline: 1.0398x; 1.0398x over previous
//
#include <hip/hip_runtime.h>
#include <math.h>

#define NBLK 64
#define NTHR 704        // 11 waves: 8 compute + dA(w8) + ae(w9) + dB(w10)
#define LSEQ 1024

typedef unsigned int u32;
typedef unsigned short u16;
typedef unsigned long long u64;

// ---------------- scalar helpers ----------------
__device__ __forceinline__ float bf2f(u16 u){ union{u32 i;float f;}v; v.i=(u32)u<<16; return v.f; }
__device__ __forceinline__ u16 f2bf(float f){ union{float f;u32 i;}v; v.f=f; u32 x=v.i;
  return (u16)((x + 0x7fffu + ((x>>16)&1u)) >> 16); }
__device__ __forceinline__ float u2f(u32 u){ union{u32 i;float f;}v; v.i=u; return v.f; }
__device__ __forceinline__ u32  f2u(float f){ union{float f;u32 i;}v; v.f=f; return v.i; }
__device__ __forceinline__ float sigm(float x){ return 1.f/(1.f+__expf(-x)); }

// coherent (agent-scope) 8B atoms: (tag<<32)|payload
__device__ __forceinline__ u64 gld64(const u64* p){ return __hip_atomic_load(const_cast<u64*>(p), __ATOMIC_RELAXED, __HIP_MEMORY_SCOPE_AGENT); }
__device__ __forceinline__ void gst64(u64* p, u64 v){ __hip_atomic_store(p, v, __ATOMIC_RELAXED, __HIP_MEMORY_SCOPE_AGENT); }
__device__ __forceinline__ u64 pollt(const u64* p, u32 tag){
  u64 v; int n = 0;
  do { v = gld64(p); } while ((u32)(v>>32) != tag && ++n < (1<<20));
  return v;
}

// ---------------- reductions ----------------
// DPP full-wave(64) sum; result uniform. VALU-only.
__device__ __forceinline__ float wred(float a){
  a += __int_as_float(__builtin_amdgcn_update_dpp(0, __float_as_int(a), 0x111, 0xf, 0xf, true));
  a += __int_as_float(__builtin_amdgcn_update_dpp(0, __float_as_int(a), 0x112, 0xf, 0xf, true));
  a += __int_as_float(__builtin_amdgcn_update_dpp(0, __float_as_int(a), 0x114, 0xf, 0xf, true));
  a += __int_as_float(__builtin_amdgcn_update_dpp(0, __float_as_int(a), 0x118, 0xf, 0xf, true));
  a += __int_as_float(__builtin_amdgcn_update_dpp(0, __float_as_int(a), 0x142, 0xa, 0xf, true));
  a += __int_as_float(__builtin_amdgcn_update_dpp(0, __float_as_int(a), 0x143, 0xc, 0xf, true));
  return __int_as_float(__builtin_amdgcn_readlane(__float_as_int(a), 63));
}
__device__ __forceinline__ float wredsh(float a){
  #pragma unroll
  for (int off = 32; off; off >>= 1) a += __shfl_xor(a, off);
  return a;
}
__device__ __forceinline__ float wredmaxsh(float a){
  #pragma unroll
  for (int off = 32; off; off >>= 1) a = fmaxf(a, __shfl_xor(a, off));
  return a;
}

// ---------------- packed dot helpers ----------------
__device__ __forceinline__ float dot8p(uint4 w, float4 a, float4 b2){
  float s;
  s  = u2f(w.x<<16)*a.x  + u2f(w.x&0xffff0000u)*a.y;
  s += u2f(w.y<<16)*a.z  + u2f(w.y&0xffff0000u)*a.w;
  s += u2f(w.z<<16)*b2.x + u2f(w.z&0xffff0000u)*b2.y;
  s += u2f(w.w<<16)*b2.z + u2f(w.w&0xffff0000u)*b2.w;
  return s;
}
__device__ __forceinline__ float dot4f(float4 w, float4 x){
  return w.x*x.x + w.y*x.y + w.z*x.z + w.w*x.w;
}
__device__ __forceinline__ uint4 pk8(float4 a, float4 b2){
  uint4 r;
  r.x = (u32)f2bf(a.x)  | ((u32)f2bf(a.y)<<16);
  r.y = (u32)f2bf(a.z)  | ((u32)f2bf(a.w)<<16);
  r.z = (u32)f2bf(b2.x) | ((u32)f2bf(b2.y)<<16);
  r.w = (u32)f2bf(b2.z) | ((u32)f2bf(b2.w)<<16);
  return r;
}

#define SMEM_BYTES 150048

// Service jobs: each on its own wave, each at most ONE poll round trip.
// wave 8: dA (stage d2) — batched 32-atom poll of XP, fire half-sum to XS.
// wave 9: ae (stage e2) — 2-way edge log-softmax from XE.
// wave 10: dB (stage d3) — joint poll of both XS halves, final dest log-softmax.
#define RUN_JOBS() do { \
  if (wv == 8 && d2V && (b == d2o1 || b == d2o2)){ \
    int half_ = (b == d2o2) ? 1 : 0; \
    const u64* P_ = XP + ((size_t)(d2Slot*64 + lane))*64 + half_*32; \
    u64 vv_[32]; int bad_; int nn_ = 0; \
    do { bad_ = 0; \
      _Pragma("unroll") for (int j_ = 0; j_ < 32; ++j_) vv_[j_] = gld64(P_ + j_); \
      _Pragma("unroll") for (int j_ = 0; j_ < 32; ++j_) bad_ |= ((u32)(vv_[j_]>>32) != d2Tag); \
    } while (bad_ && ++nn_ < (1<<20)); \
    float h0_ = 0.f, h1_ = 0.f; \
    _Pragma("unroll") for (int j_ = 0; j_ < 32; ++j_){ \
      h0_ += bf2f((u16)(vv_[j_] & 0xffff)); h1_ += bf2f((u16)((vv_[j_]>>16) & 0xffff)); } \
    gst64(&XS[half_*256 + d2Slot*64 + lane], ((u64)d2Tag<<32) | (u32)f2bf(h0_) | ((u32)f2bf(h1_)<<16)); \
  } \
  if (wv == 10 && d3V && b == d3o1){ \
    const u64* pa_ = &XS[d3Slot*64 + lane]; \
    const u64* pb_ = &XS[256 + d3Slot*64 + lane]; \
    u64 va_, vb_; int nn_ = 0; \
    do { va_ = gld64(pa_); vb_ = gld64(pb_); } \
    while ((((u32)(va_>>32) != d3Tag) || ((u32)(vb_>>32) != d3Tag)) && ++nn_ < (1<<20)); \
    float x0 = bf2f((u16)(va_ & 0xffff)) + bf2f((u16)(vb_ & 0xffff)); \
    float x1 = bf2f((u16)((va_>>16) & 0xffff)) + bf2f((u16)((vb_>>16) & 0xffff)); \
    x0 = (lane < d3cur)      ? x0 : -__builtin_inff(); \
    x1 = (lane + 64 < d3cur) ? x1 : -__builtin_inff(); \
    float m_ = wredmaxsh(fmaxf(x0, x1)); \
    float s_ = wredsh(__expf(x0 - m_) + __expf(x1 - m_)); \
    float la_ = (d3arg < 64) ? __shfl(x0, d3arg) : __shfl(x1, d3arg - 64); \
    if (lane == 0) nllw += (m_ + logf(s_)) - la_; \
  } \
  if (wv == 9 && e2V && b == e2Own){ \
    u64 v_ = pollt(XE + e2Slot*64 + lane, e2Tag); \
    float p0_ = wredsh(bf2f((u16)(v_ & 0xffff))); \
    float p1_ = wredsh(bf2f((u16)((v_>>16) & 0xffff))); \
    if (lane == 0){ \
      float l0_ = p0_ + be2_0, l1_ = p1_ + be2_1; \
      float m_ = fmaxf(l0_, l1_); \
      nllw += m_ + logf(__expf(l0_-m_) + __expf(l1_-m_)) - (e2Sel ? l1_ : l0_); \
    } \
  } \
} while(0)

#define SHIFT3() do { \
  d3V=d2V; d3Slot=d2Slot; d3o1=d2o1; d3Tag=d2Tag; d3cur=d2cur; d3arg=d2arg; \
  d2V=d1V; d2Slot=d1Slot; d2o1=d1o1; d2o2=d1o2; d2Tag=d1Tag; d2cur=d1cur; d2arg=d1arg; \
  d1V=0; \
  e2V=e1V; e2Slot=e1Slot; e2Own=e1Own; e2Tag=e1Tag; e2Sel=e1Sel; \
  e1V=0; \
} while(0)

__global__ void __launch_bounds__(NTHR, 1)
dgmg_kernel(const int* __restrict__ actions, const int* __restrict__ argseq,
            const float* __restrict__ node_init, const float* __restrict__ w_nip, const float* __restrict__ b_nip,
            const float* __restrict__ w_e1, const float* __restrict__ b_e1,
            const float* __restrict__ w_e2, const float* __restrict__ b_e2,
            const float* __restrict__ w_q, const float* __restrict__ b_q,
            const float* __restrict__ w_k,
            const float* __restrict__ wih_n, const float* __restrict__ whh_n,
            const float* __restrict__ bih_n, const float* __restrict__ bhh_n,
            const float* __restrict__ wih_g, const float* __restrict__ whh_g,
            const float* __restrict__ bih_g, const float* __restrict__ bhh_g,
            const float* __restrict__ graph0,
            float* __restrict__ out, unsigned char* __restrict__ ws)
{
  extern __shared__ unsigned char smem[];
  u16* s_wihg = (u16*)smem;                 // [24][512] packed bf16
  u16* s_whhg = s_wihg + 24*512;
  u16* s_wihn = s_whhg + 24*512;
  u16* s_whhn = s_wihn + 24*512;
  u16* s_we1  = s_whhn + 24*512;            // [8][1024]
  u16* s_wq   = s_we1 + 8*1024;             // [8][1024]
  float* s_g    = (float*)(s_wq + 8*1024);  // staged graph vector
  float* s_nc   = s_g + 512;                // staged ncur
  float* s_curv = s_nc + 512;               // current node vector pre-update
  float* s_h0   = s_curv + 512;             // fresh-node embedding
  float* s_kloc = s_h0 + 512;               // [8][128] k-cache transposed [dim][node]
  float* s_bihg = s_kloc + 1024;            // [24]
  float* s_bhhg = s_bihg + 24;
  float* s_bihn = s_bhhg + 24;
  float* s_bhhn = s_bihn + 24;
  float* s_be1  = s_bhhn + 24;              // [8]
  float* s_bq   = s_be1 + 8;                // [8]
  float* s_q8   = s_bq + 8;                 // [8]
  float* s_red  = s_q8 + 8;                 // [16]
  u16*   s_gin  = (u16*)(s_red + 16);       // [128][24] gi_n freeze cache (bf16)

  const int b = blockIdx.x, tid = threadIdx.x;
  const int wv = tid >> 6, lane = tid & 63;
  const int d = b*8 + ((wv < 8) ? wv : 0);

  // workspace: tagged u64 atoms
  u64* Xng = (u64*)ws;         // [2][512][2]: per dim {ncur, g} adjacent
  u64* Xh  = Xng + 2048;       // [512] h0 broadcast
  u64* XE  = Xh + 512;         // [4][64] edge-logit partials (2xbf16)
  u64* XP  = XE + 256;         // [4][64][64] dest-logit partials
  u64* XS  = XP + 16384;       // [2][4][64] dest half-sums (both halves)
  u64* XN  = XS + 512;         // [128] final nll pieces (wave9 | wave10)

  // ---------------- init: biases + packed bf16 weight slices ----------------
  if (tid < 24){
    int ld = tid/3, gt = tid%3;
    int row = gt*512 + b*8 + ld;
    s_bihg[tid] = bih_g[row]; s_bhhg[tid] = bhh_g[row];
    s_bihn[tid] = bih_n[row]; s_bhhn[tid] = bhh_n[row];
  }
  if (tid < 8){ s_be1[tid] = b_e1[b*8+tid]; s_bq[tid] = b_q[b*8+tid]; }

  for (int r = wv; r < 24; r += 11){          // all 11 waves pack
    int ld = r/3, gt = r%3;
    long grow = (long)(gt*512 + b*8 + ld) * 512;
    float4 a0, a1;
    a0 = *(const float4*)&wih_g[grow + lane*8]; a1 = *(const float4*)&wih_g[grow + lane*8 + 4];
    *(uint4*)&s_wihg[r*512 + lane*8] = pk8(a0, a1);
    a0 = *(const float4*)&whh_g[grow + lane*8]; a1 = *(const float4*)&whh_g[grow + lane*8 + 4];
    *(uint4*)&s_whhg[r*512 + lane*8] = pk8(a0, a1);
    a0 = *(const float4*)&wih_n[grow + lane*8]; a1 = *(const float4*)&wih_n[grow + lane*8 + 4];
    *(uint4*)&s_wihn[r*512 + lane*8] = pk8(a0, a1);
    a0 = *(const float4*)&whh_n[grow + lane*8]; a1 = *(const float4*)&whh_n[grow + lane*8 + 4];
    *(uint4*)&s_whhn[r*512 + lane*8] = pk8(a0, a1);
  }
  if (wv < 8){
    long grow = (long)(b*8 + wv) * 1024;
    #pragma unroll
    for (int h = 0; h < 2; ++h){
      float4 a0 = *(const float4*)&w_e1[grow + h*512 + lane*8];
      float4 a1 = *(const float4*)&w_e1[grow + h*512 + lane*8 + 4];
      *(uint4*)&s_we1[wv*1024 + h*512 + lane*8] = pk8(a0, a1);
      float4 q0 = *(const float4*)&w_q[grow + h*512 + lane*8];
      float4 q1 = *(const float4*)&w_q[grow + h*512 + lane*8 + 4];
      *(uint4*)&s_wq[wv*1024 + h*512 + lane*8] = pk8(q0, q1);
    }
  }
  float we2_0 = w_e2[d], we2_1 = w_e2[512+d];
  float be2_0 = b_e2[0], be2_1 = b_e2[1];
  float nllw = 0.f;

  // job pipeline state (uniform trace walk on every thread)
  int d1V=0,d1Slot=0,d1o1=0,d1o2=0,d1cur=0,d1arg=0; u32 d1Tag=0;
  int d2V=0,d2Slot=0,d2o1=0,d2o2=0,d2cur=0,d2arg=0; u32 d2Tag=0;
  int d3V=0,d3Slot=0,d3o1=0,d3cur=0,d3arg=0; u32 d3Tag=0;
  int e1V=0,e1Slot=0,e1Own=0,e1Sel=0; u32 e1Tag=0;
  int e2V=0,e2Slot=0,e2Own=0,e2Sel=0; u32 e2Tag=0;
  int ecnt=0, dcnt=0;

  // ---------------- INIT (tag 1): broadcast h0 ----------------
  if (tid < 512) s_g[tid] = node_init[tid];   // scratch
  __syncthreads();
  float cbg_r=0,cbg_z=0,bg_ni=0,bg_nh=0, bh_gr=0,bh_gz=0;
  float bn_r=0,bn_z=0,bn_nh=0, fb_r=0,fb_z=0,fb_n=0, be1w=0,bqw=0;
  if (wv < 8){
    cbg_r = s_bihg[wv*3+0]+s_bhhg[wv*3+0];
    cbg_z = s_bihg[wv*3+1]+s_bhhg[wv*3+1];
    bg_ni = s_bihg[wv*3+2]; bg_nh = s_bhhg[wv*3+2];
    bh_gr = s_bhhg[wv*3+0]; bh_gz = s_bhhg[wv*3+1];
    bn_r = s_bhhn[wv*3+0]; bn_z = s_bhhn[wv*3+1]; bn_nh = s_bhhn[wv*3+2];
    fb_r = s_bihn[wv*3+0]; fb_z = s_bihn[wv*3+1]; fb_n = s_bihn[wv*3+2];
    be1w = s_be1[wv]; bqw = s_bq[wv];
    const float* wr = w_nip + (long)d*512;
    float4 wa = *(const float4*)&wr[lane*8], wb2 = *(const float4*)&wr[lane*8+4];
    float4 xa = *(float4*)&s_g[lane*8], xb = *(float4*)&s_g[lane*8+4];
    float h0d = wred(dot4f(wa,xa)+dot4f(wb2,xb)) + b_nip[d];
    if (lane == 0) gst64(&Xh[d], (1ull<<32) | f2u(h0d));
  }
  __syncthreads();
  u32 ph = 2;

  float gi0r=0,gi0z=0,gi0n=0, ghn0r=0,ghn0z=0,ghn0n=0;  // caches of *@h0
  int cur = -1, have_se = 0;
  bool first_an = true;

  // ---------------- main sequential scan ----------------
  for (int t = 0; t < LSEQ; ++t){
    int a = actions[t];
    if (a == 1) continue;                    // ADD_EDGE fused into its CD phase
    if (a == 3){ have_se = 1; continue; }    // STOP_EDGE fused into next AN / drain
    if (a < 0 || a >= 4) continue;

    int t1 = (t+1 < LSEQ) ? actions[t+1] : -1;
    int nxt = (t1 == 1);
    int i2 = (t+2 < LSEQ) ? t+2 : LSEQ-1;
    int chn = nxt ? argseq[i2] : 0;          // lookahead: next edge's destination

    u32 tg = ph-1;

    if (a == 0){ // ======== ADD_NODE: 1 phase, 2 barriers ========
      int eslot = ecnt & 3;
      if (first_an){
        if (tid < 512){ u64 v = pollt(&Xh[tid], 1u); s_h0[tid] = u2f((u32)v); s_g[tid] = graph0[tid]; }
      } else {
        if (tid < 512){ u64 v = pollt(&Xng[((tg&1)*512+tid)*2+1], tg); s_g[tid] = u2f((u32)v); }
      }
      __syncthreads();
      RUN_JOBS();
      if (wv < 8){
        float4 xg_a = *(float4*)&s_g[lane*8], xg_b = *(float4*)&s_g[lane*8+4];
        float4 xc_a = *(float4*)&s_curv[lane*8], xc_b = *(float4*)&s_curv[lane*8+4];
        const u32* Whg = (const u32*)s_whhg;
        if (first_an){
          float4 xh_a = *(float4*)&s_h0[lane*8], xh_b = *(float4*)&s_h0[lane*8+4];
          const u32* Wig = (const u32*)s_wihg; const u32* Wn = (const u32*)s_whhn;
          gi0r = wred(dot8p(*(const uint4*)&Wig[(wv*3+0)*256+lane*4], xh_a,xh_b)) + s_bihg[wv*3+0];
          gi0z = wred(dot8p(*(const uint4*)&Wig[(wv*3+1)*256+lane*4], xh_a,xh_b)) + s_bihg[wv*3+1];
          gi0n = wred(dot8p(*(const uint4*)&Wig[(wv*3+2)*256+lane*4], xh_a,xh_b)) + s_bihg[wv*3+2];
          ghn0r = wred(dot8p(*(const uint4*)&Wn[(wv*3+0)*256+lane*4], xh_a,xh_b)) + bn_r;
          ghn0z = wred(dot8p(*(const uint4*)&Wn[(wv*3+1)*256+lane*4], xh_a,xh_b)) + bn_z;
          ghn0n = wred(dot8p(*(const uint4*)&Wn[(wv*3+2)*256+lane*4], xh_a,xh_b)) + bn_nh;
        }
        { // fire g' FIRST (critical cross-block chain)
          float ghr = wred(dot8p(*(const uint4*)&Whg[(wv*3+0)*256+lane*4], xg_a,xg_b)) + bh_gr;
          float ghz = wred(dot8p(*(const uint4*)&Whg[(wv*3+1)*256+lane*4], xg_a,xg_b)) + bh_gz;
          float ghn = wred(dot8p(*(const uint4*)&Whg[(wv*3+2)*256+lane*4], xg_a,xg_b)) + bg_nh;
          float r_ = sigm(gi0r + ghr), z_ = sigm(gi0z + ghz);
          float n_ = tanhf(gi0n + r_*ghn);
          if (lane == 0) gst64(&Xng[((ph&1)*512+d)*2+1], ((u64)ph<<32) | f2u((1.f-z_)*n_ + z_*s_g[d]));
        }
        float fr=0.f, fz=0.f, fn=0.f;
        if (cur >= 0){ // freeze prev node BEFORE lookahead read
          const u32* Win = (const u32*)s_wihn;
          fr = wred(dot8p(*(const uint4*)&Win[(wv*3+0)*256+lane*4], xc_a,xc_b)) + fb_r;
          fz = wred(dot8p(*(const uint4*)&Win[(wv*3+1)*256+lane*4], xc_a,xc_b)) + fb_z;
          fn = wred(dot8p(*(const uint4*)&Win[(wv*3+2)*256+lane*4], xc_a,xc_b)) + fb_n;
          const float* wkr = w_k + (long)d*512;
          float4 ka = *(const float4*)&wkr[lane*8], kb2 = *(const float4*)&wkr[lane*8+4];
          float kv = wred(dot4f(ka,xc_a)+dot4f(kb2,xc_b));
          if (lane == 0){
            s_gin[cur*24+wv*3+0] = f2bf(fr); s_gin[cur*24+wv*3+1] = f2bf(fz); s_gin[cur*24+wv*3+2] = f2bf(fn);
            s_kloc[wv*128 + cur] = kv;
          }
        }
        if (nxt){ // ncur1 = GRU_n(chosen1, h0); forward freeze regs if chn==cur
          float gr = (chn == cur) ? fr : bf2f(s_gin[chn*24+wv*3+0]);
          float gz = (chn == cur) ? fz : bf2f(s_gin[chn*24+wv*3+1]);
          float gn = (chn == cur) ? fn : bf2f(s_gin[chn*24+wv*3+2]);
          float r2 = sigm(gr + ghn0r), z2 = sigm(gz + ghn0z);
          float n2 = tanhf(gn + r2*ghn0n);
          if (lane == 0) gst64(&Xng[((ph&1)*512+d)*2], ((u64)ph<<32) | f2u((1.f-z2)*n2 + z2*s_h0[d]));
        }
        if (have_se){ // deferred STOP_EDGE e-logit partials
          const u32* Re = (const u32*)s_we1 + wv*512;
          float pe = dot8p(*(const uint4*)&Re[lane*4], xg_a,xg_b) + dot8p(*(const uint4*)&Re[256+lane*4], xc_a,xc_b);
          float hv = fmaxf(wred(pe) + be1w, 0.f);
          if (lane == 0){ s_red[wv*2] = hv*we2_0; s_red[wv*2+1] = hv*we2_1; }
        }
      }
      __syncthreads();
      if (have_se && tid == 0){
        float p0 = 0.f, p1 = 0.f;
        #pragma unroll
        for (int i = 0; i < 8; ++i){ p0 += s_red[i*2]; p1 += s_red[i*2+1]; }
        gst64(&XE[eslot*64 + b], ((u64)ph<<32) | (u32)f2bf(p0) | ((u32)f2bf(p1)<<16));
      }
      if (tid < 512) s_curv[tid] = s_h0[tid];
      SHIFT3();
      if (have_se){ e1V=1; e1Slot=eslot; e1Sel=1; e1Own=ecnt&63; e1Tag=ph; ecnt++; }
      have_se = 0; first_an = false;
      cur += 1; ph += 1;
    }
    else { // ======== CHOOSE_DEST: 1 phase, 2 barriers (AE fused; ncur pipelined) ========
      int arg = argseq[t];
      int eslot = ecnt & 3, dslot = dcnt & 3;
      if (tid < 512){
        const u64* p = &Xng[((tg&1)*512 + tid)*2];
        u64 v0, v1; int n = 0;
        do { v0 = gld64(p); v1 = gld64(p+1); }
        while ((((u32)(v0>>32) != tg) || ((u32)(v1>>32) != tg)) && ++n < (1<<20));
        s_nc[tid] = u2f((u32)v0); s_g[tid] = u2f((u32)v1);
      }
      __syncthreads();
      RUN_JOBS();
      if (wv < 8){
        float4 xn_a = *(float4*)&s_nc[lane*8], xn_b = *(float4*)&s_nc[lane*8+4];
        float4 xg_a = *(float4*)&s_g[lane*8],  xg_b = *(float4*)&s_g[lane*8+4];
        float4 xc_a = *(float4*)&s_curv[lane*8], xc_b = *(float4*)&s_curv[lane*8+4];
        const u32* Wn = (const u32*)s_whhn; const u32* Wig = (const u32*)s_wihg; const u32* Whg = (const u32*)s_whhg;
        { // 1) fire g_j FIRST (critical cross-block chain)
          float pr = dot8p(*(const uint4*)&Wig[(wv*3+0)*256+lane*4], xn_a,xn_b)
                   + dot8p(*(const uint4*)&Whg[(wv*3+0)*256+lane*4], xg_a,xg_b);
          float pz = dot8p(*(const uint4*)&Wig[(wv*3+1)*256+lane*4], xn_a,xn_b)
                   + dot8p(*(const uint4*)&Whg[(wv*3+1)*256+lane*4], xg_a,xg_b);
          float r_ = sigm(wred(pr) + cbg_r);
          float z_ = sigm(wred(pz) + cbg_z);
          float gin_ = wred(dot8p(*(const uint4*)&Wig[(wv*3+2)*256+lane*4], xn_a,xn_b)) + bg_ni;
          float ghn_ = wred(dot8p(*(const uint4*)&Whg[(wv*3+2)*256+lane*4], xg_a,xg_b)) + bg_nh;
          float n_ = tanhf(gin_ + r_*ghn_);
          if (lane == 0) gst64(&Xng[((ph&1)*512+d)*2+1], ((u64)ph<<32) | f2u((1.f-z_)*n_ + z_*s_g[d]));
        }
        if (nxt){ // 2) fire ncur_{j+1} = GRU_n(chosen_{j+1}, ncur_j)
          float ghr = wred(dot8p(*(const uint4*)&Wn[(wv*3+0)*256+lane*4], xn_a,xn_b)) + bn_r;
          float ghz = wred(dot8p(*(const uint4*)&Wn[(wv*3+1)*256+lane*4], xn_a,xn_b)) + bn_z;
          float ghn = wred(dot8p(*(const uint4*)&Wn[(wv*3+2)*256+lane*4], xn_a,xn_b)) + bn_nh;
          float gr = bf2f(s_gin[chn*24+wv*3+0]), gz = bf2f(s_gin[chn*24+wv*3+1]), gn = bf2f(s_gin[chn*24+wv*3+2]);
          float r_ = sigm(gr+ghr), z_ = sigm(gz+ghz);
          float n_ = tanhf(gn + r_*ghn);
          if (lane == 0) gst64(&Xng[((ph&1)*512+d)*2], ((u64)ph<<32) | f2u((1.f-z_)*n_ + z_*s_nc[d]));
        }
        { // 3) q_j + AE e-partials from (g_{j-1}, curv_{j-1})
          const u32* Rq = (const u32*)s_wq + wv*512;
          float pq = dot8p(*(const uint4*)&Rq[lane*4], xg_a,xg_b) + dot8p(*(const uint4*)&Rq[256+lane*4], xc_a,xc_b);
          float qd = wred(pq) + bqw;
          const u32* Re = (const u32*)s_we1 + wv*512;
          float pe = dot8p(*(const uint4*)&Re[lane*4], xg_a,xg_b) + dot8p(*(const uint4*)&Re[256+lane*4], xc_a,xc_b);
          float hv = fmaxf(wred(pe) + be1w, 0.f);
          if (lane == 0){ s_q8[wv] = qd; s_red[wv*2] = hv*we2_0; s_red[wv*2+1] = hv*we2_1; }
        }
      }
      __syncthreads();
      if (tid < 64){ // dest-logit partials: local k slices x local q dims
        float pl0 = 0.f, pl1 = 0.f;
        #pragma unroll
        for (int k = 0; k < 8; ++k){
          pl0 += s_kloc[k*128 + tid]      * s_q8[k];
          pl1 += s_kloc[k*128 + tid + 64] * s_q8[k];
        }
        gst64(&XP[((size_t)(dslot*64 + tid))*64 + b], ((u64)ph<<32) | (u32)f2bf(pl0) | ((u32)f2bf(pl1)<<16));
      }
      if (tid == 64){
        float p0 = 0.f, p1 = 0.f;
        #pragma unroll
        for (int i = 0; i < 8; ++i){ p0 += s_red[i*2]; p1 += s_red[i*2+1]; }
        gst64(&XE[eslot*64 + b], ((u64)ph<<32) | (u32)f2bf(p0) | ((u32)f2bf(p1)<<16));
      }
      if (tid < 512) s_curv[tid] = s_nc[tid];
      SHIFT3();
      e1V=1; e1Slot=eslot; e1Sel=0; e1Own=ecnt&63; e1Tag=ph; ecnt++;
      d1V=1; d1Slot=dslot; d1o1=(2*dcnt)&63; d1o2=(2*dcnt+1)&63; d1cur=cur; d1arg=arg; d1Tag=ph; dcnt++;
      ph += 1;
    }
  }

  // ---------------- drain: SE phase + 3 flush phases ----------------
  {
    int eslot = ecnt & 3;
    u32 tg = ph-1;
    if (tid < 512){ u64 v = pollt(&Xng[((tg&1)*512+tid)*2+1], tg); s_g[tid] = u2f((u32)v); }
    __syncthreads();
    RUN_JOBS();
    if (have_se && wv < 8){
      float4 xg_a = *(float4*)&s_g[lane*8], xg_b = *(float4*)&s_g[lane*8+4];
      float4 xc_a = *(float4*)&s_curv[lane*8], xc_b = *(float4*)&s_curv[lane*8+4];
      const u32* Re = (const u32*)s_we1 + wv*512;
      float pe = dot8p(*(const uint4*)&Re[lane*4], xg_a,xg_b) + dot8p(*(const uint4*)&Re[256+lane*4], xc_a,xc_b);
      float hv = fmaxf(wred(pe) + be1w, 0.f);
      if (lane == 0){ s_red[wv*2] = hv*we2_0; s_red[wv*2+1] = hv*we2_1; }
    }
    __syncthreads();
    if (have_se && tid == 0){
      float p0 = 0.f, p1 = 0.f;
      #pragma unroll
      for (int i = 0; i < 8; ++i){ p0 += s_red[i*2]; p1 += s_red[i*2+1]; }
      gst64(&XE[eslot*64 + b], ((u64)ph<<32) | (u32)f2bf(p0) | ((u32)f2bf(p1)<<16));
    }
    SHIFT3();
    if (have_se){ e1V=1; e1Slot=eslot; e1Sel=1; e1Own=ecnt&63; e1Tag=ph; ecnt++; }
    ph += 1;
  }
  #pragma unroll 1
  for (int dp = 0; dp < 3; ++dp){
    __syncthreads();
    RUN_JOBS();
    SHIFT3();
    ph += 1;
  }
  // ---------------- final collect ----------------
  if (wv == 9  && lane == 0) gst64(&XN[b],      (0xFFFFull<<32) | f2u(nllw));
  if (wv == 10 && lane == 0) gst64(&XN[64 + b], (0xFFFFull<<32) | f2u(nllw));
  if (b == 0 && wv == 8){
    u64 va = pollt(&XN[lane], 0xFFFFu);
    u64 vb = pollt(&XN[64 + lane], 0xFFFFu);
    float tot = wredsh(u2f((u32)va) + u2f((u32)vb));
    if (lane == 0) out[0] = tot;
  }
}

extern "C" void kernel_launch(void* const* d_in, const int* in_sizes, int n_in,
                              void* d_out, int out_size, void* d_ws, size_t ws_size,
                              hipStream_t stream) {
  (void)in_sizes; (void)n_in; (void)out_size; (void)ws_size;
  // zero all tag-atom regions (19840 u64) — exact-match tags then poison/replay-safe
  hipMemsetAsync(d_ws, 0, 158720, stream);
  hipFuncSetAttribute((const void*)dgmg_kernel,
                      hipFuncAttributeMaxDynamicSharedMemorySize, SMEM_BYTES);
  dgmg_kernel<<<NBLK, NTHR, SMEM_BYTES, stream>>>(
      (const int*)d_in[0], (const int*)d_in[1],
      (const float*)d_in[2], (const float*)d_in[3], (const float*)d_in[4],
      (const float*)d_in[5], (const float*)d_in[6],
      (const float*)d_in[7], (const float*)d_in[8],
      (const float*)d_in[9], (const float*)d_in[10],
      (const float*)d_in[11],                      /* w_k ; b_k unused (cancels) */
      (const float*)d_in[13], (const float*)d_in[14],
      (const float*)d_in[15], (const float*)d_in[16],
      (const float*)d_in[17], (const float*)d_in[18],
      (const float*)d_in[19], (const float*)d_in[20],
      (const float*)d_in[21],
      (float*)d_out, (unsigned char*)d_ws);
}